// Round 15
// baseline (46.644 us; speedup 1.0000x reference)
//
#include <hip/hip_runtime.h>
#include <stdint.h>

// Problem constants
#define BB 1024
#define MM 128
#define KK 32
#define NEDGE (BB * MM * KK)   // 4194304
#define ROWS_PER_WAVE 32       // BPB = 1: one block per batch, 32 rows/wave

#define TH  0x41C80000u        // f32 bits of 25.0  (low 7 bits zero)
#define T2  0x41480000u        // f32 bits of 12.5  (low 7 bits zero)
#define INFK 0x7F800000u

typedef unsigned int uint2v __attribute__((ext_vector_type(2)));

#define DPP1 "quad_perm:[1,0,3,2] row_mask:0xf bank_mask:0xf"   // xor 1
#define DPP2 "quad_perm:[2,3,0,1] row_mask:0xf bank_mask:0xf"   // xor 2

// ---- single-key comparators (keep-min where mask bit set) ----
template<int ST>
static __device__ __forceinline__ void cexd(unsigned& k, unsigned long long msk) {
    unsigned t0, t1;
    if constexpr (ST == 1) {
        asm("s_nop 1\n\t"
            "v_min_u32_dpp %1, %0, %0 " DPP1 "\n\t"
            "v_max_u32_dpp %2, %0, %0 " DPP1 "\n\t"
            "v_cndmask_b32 %0, %2, %1, %3"
            : "+v"(k), "=&v"(t0), "=&v"(t1) : "s"(msk));
    } else {
        asm("s_nop 1\n\t"
            "v_min_u32_dpp %1, %0, %0 " DPP2 "\n\t"
            "v_max_u32_dpp %2, %0, %0 " DPP2 "\n\t"
            "v_cndmask_b32 %0, %2, %1, %3"
            : "+v"(k), "=&v"(t0), "=&v"(t1) : "s"(msk));
    }
}

template<int ST>
static __device__ __forceinline__ void cexs(unsigned& k, unsigned long long msk) {
    unsigned p = (unsigned)__builtin_amdgcn_ds_swizzle((int)k, (ST << 10) | 0x1F);
    unsigned mn = __builtin_elementwise_min(k, p);
    unsigned mx = __builtin_elementwise_max(k, p);
    asm("v_cndmask_b32 %0, %1, %2, %3" : "=v"(k) : "v"(mx), "v"(mn), "s"(msk));
}

// stride-32 compare-exchange across the 32-lane halves
static __device__ __forceinline__ void cex32f(unsigned& k, unsigned long long msk) {
#if __has_builtin(__builtin_amdgcn_permlane32_swap)
    uint2v s = __builtin_amdgcn_permlane32_swap(k, k, false, false);
    unsigned mn = __builtin_elementwise_min(s.x, s.y);
    unsigned mx = __builtin_elementwise_max(s.x, s.y);
#else
    unsigned p = (unsigned)__shfl_xor((int)k, 32, 64);
    unsigned mn = __builtin_elementwise_min(k, p);
    unsigned mx = __builtin_elementwise_max(k, p);
#endif
    asm("v_cndmask_b32 %0, %1, %2, %3" : "=v"(k) : "v"(mx), "v"(mn), "s"(msk));
}

// min over {v[l], v[l^32]}
static __device__ __forceinline__ unsigned minxor32(unsigned k) {
#if __has_builtin(__builtin_amdgcn_permlane32_swap)
    uint2v s = __builtin_amdgcn_permlane32_swap(k, k, false, false);
    return __builtin_elementwise_min(s.x, s.y);
#else
    unsigned p = (unsigned)__shfl_xor((int)k, 32, 64);
    return __builtin_elementwise_min(k, p);
#endif
}

// duplicate lanes 0..31 into lanes 32..63
static __device__ __forceinline__ unsigned duphalf(unsigned k, unsigned long long m32) {
#if __has_builtin(__builtin_amdgcn_permlane32_swap)
    uint2v s = __builtin_amdgcn_permlane32_swap(k, k, false, false);
    unsigned partner = s.x ^ s.y ^ k;
#else
    unsigned partner = (unsigned)__shfl_xor((int)k, 32, 64);
#endif
    unsigned r;
    asm("v_cndmask_b32 %0, %1, %2, %3" : "=v"(r) : "v"(partner), "v"(k), "s"(m32));
    return r;
}

static __device__ __forceinline__ unsigned mbcnt64(unsigned long long m) {
    unsigned t = __builtin_amdgcn_mbcnt_lo((unsigned)m, 0u);
    return __builtin_amdgcn_mbcnt_hi((unsigned)(m >> 32), t);
}

// grid = BB blocks of 256 threads (one block per batch); each wave: 32 rows.
// key = (f32bits(max(d2,0)) & ~0x7F) | j.
// Fast (n<=64, ~91%): compact + 21-stage sort-64.
// Refast (n>64 but 32<=n2<=64 under T2=12.5, ~9%): compacting under T2 is
//   exact (>=32 survivors < T2 ==> top-32 under 25 all < T2) -> same sort-64.
// Slow (pathological, ~0%): round-9 two-key network.
__global__ __launch_bounds__(256, 4) void knn_edges_kernel(const float* __restrict__ pos,
                                                           float* __restrict__ out) {
    __shared__ float px[MM], py[MM], pz[MM], sqs[MM];
    __shared__ unsigned comp[4][64];
    const int b = blockIdx.x;
    const int tid = threadIdx.x;

    if (tid < MM) {
        const float* p = pos + (size_t)(b * MM + tid) * 3;
        float x = p[0], y = p[1], z = p[2];
        px[tid] = x; py[tid] = y; pz[tid] = z;
        sqs[tid] = __fadd_rn(__fadd_rn(__fmul_rn(x, x), __fmul_rn(y, y)), __fmul_rn(z, z));
    }
    __syncthreads();

    const int wave = tid >> 6;
    const int lane = tid & 63;
    const int g = lane & 31;
    const bool hi = lane >= 32;
    const unsigned upper = hi ? ~0u : 0u;

    // ---- the 6 comparator masks, anchored once into SGPR pairs ----
    unsigned long long m1  = 0x5555555555555555ull;
    unsigned long long m2  = 0x3333333333333333ull;
    unsigned long long m4  = 0x0F0F0F0F0F0F0F0Full;
    unsigned long long m8  = 0x00FF00FF00FF00FFull;
    unsigned long long m16 = 0x0000FFFF0000FFFFull;
    unsigned long long m32 = 0x00000000FFFFFFFFull;
    asm("" : "+s"(m1), "+s"(m2), "+s"(m4), "+s"(m8), "+s"(m16), "+s"(m32));

    // ---- fast-path fold constants (full-lane based) ----
    auto ff = [&](int s) -> unsigned { return (lane & s) ? ~0u : 0u; };
    const unsigned u2    = ff(2);
    const unsigned s24   = u2 ^ ff(4);
    const unsigned s48   = ff(4) ^ ff(8);
    const unsigned s816  = ff(8) ^ ff(16);
    const unsigned s1632 = ff(16) ^ ff(32);
    const unsigned u32   = ff(32);

    // ---- slow-path direction-fold constants (g-based, verified round 9) ----
    auto dmask = [&](int s) -> unsigned {
        unsigned zer = ((g & s) == 0) ? ~0u : 0u;
        return ~(zer ^ upper);   // XNOR
    };
    const unsigned f2    = dmask(2);
    const unsigned nf2   = ~f2;
    const unsigned f4c   = dmask(4);
    const unsigned f8c   = dmask(8);
    const unsigned f16c  = dmask(16);
    const unsigned f32c  = dmask(32);
    const unsigned t24   = f2 ^ f4c;
    const unsigned t48   = f4c ^ f8c;
    const unsigned t816  = f8c ^ f16c;
    const unsigned t1632 = f16c ^ f32c;
    const unsigned nf32  = ~f32c;

    // slow path (round-9 verified two-key network) — executes ~never
    auto slow_sort = [&](unsigned k0r, unsigned k1r) -> unsigned {
        unsigned K0 = k0r ^ f2;
        unsigned K1 = k1r ^ nf2;
#define SS2(ST, MSK) cexs<ST>(K0, MSK); cexs<ST>(K1, MSK);
        SS2(1, m1)
        K0 ^= t24; K1 ^= t24;
        SS2(2, m2) SS2(1, m1)
        K0 ^= t48; K1 ^= t48;
        SS2(4, m4) SS2(2, m2) SS2(1, m1)
        K0 ^= t816; K1 ^= t816;
        SS2(8, m8) SS2(4, m4) SS2(2, m2) SS2(1, m1)
        K0 ^= t1632; K1 ^= t1632;
        SS2(16, m16) SS2(8, m8) SS2(4, m4) SS2(2, m2) SS2(1, m1)
#undef SS2
        unsigned Ca = (__builtin_elementwise_min(K0 ^ f32c, K1 ^ nf32)) ^ upper;
        cexs<16>(Ca, m16); cexs<8>(Ca, m8); cexs<4>(Ca, m4);
        cexs<2>(Ca, m2);  cexs<1>(Ca, m1);
        unsigned Ma = minxor32(Ca ^ upper);
        cexs<16>(Ma, m16); cexs<8>(Ma, m8); cexs<4>(Ma, m4);
        cexs<2>(Ma, m2);  cexs<1>(Ma, m1);
        return Ma;
    };

    // per-lane candidate coordinates, hoisted across the row loop
    const int j0 = lane, j1 = lane + 64;
    const float xa = px[j0], ya = py[j0], za = pz[j0], qa = sqs[j0];
    const float xb = px[j1], yb = py[j1], zb = pz[j1], qb = sqs[j1];

    const int row0 = wave * ROWS_PER_WAVE;
    const float fbase = (float)(b * MM);   // exact in fp32

    // output streams (3 stores/lane/row):
    //  lanes <32 : pA=src (KK), pB=vec.x (3KK), pC=vec.y (3KK)
    //  lanes >=32: pA=dst (KK), pB=vec.z (3KK), pC=weight (KK)
    float* const vecbase = out + 3 * (size_t)NEDGE;
    const long e0 = (long)(b * MM + row0) * KK + g;
    float* pA = hi ? out + (size_t)NEDGE + e0 : out + e0;
    float* pB = vecbase + e0 * 3 + (hi ? 2 : 0);
    float* pC = hi ? out + 2 * (size_t)NEDGE + e0 : vecbase + e0 * 3 + 1;
    const int sC = hi ? KK : 3 * KK;

    float fnode = fbase + (float)row0;

#pragma unroll 1
    for (int ii = 0; ii < ROWS_PER_WAVE; ++ii) {
        const int i = row0 + ii;
        const float xi = px[i], yi = py[i], zi = pz[i], qi = sqs[i];

        // ---- raw candidate keys ----
        float dot0 = fmaf(xi, xa, fmaf(yi, ya, zi * za));
        unsigned k0r = (__float_as_uint(fmaxf(fmaf(-2.0f, dot0, qi + qa), 0.0f)) & 0xFFFFFF80u) | (unsigned)j0;
        float dot1 = fmaf(xi, xb, fmaf(yi, yb, zi * zb));
        unsigned k1r = (__float_as_uint(fmaxf(fmaf(-2.0f, dot1, qi + qb), 0.0f)) & 0xFFFFFF80u) | (unsigned)j1;

        // ---- census under 25.0 (wave-uniform) ----
        unsigned long long mask0 = __ballot(k0r < TH);
        unsigned long long mask1 = __ballot(k1r < TH);
        unsigned c0 = (unsigned)__popcll(mask0);
        unsigned n  = c0 + (unsigned)__popcll(mask1);

        bool sortable = (n <= 64u);
        if (!sortable) {
            // dense row: re-census under T2 = 12.5; compacting under T2 is
            // exact when 32 <= n2 <= 64
            mask0 = __ballot(k0r < T2);
            mask1 = __ballot(k1r < T2);
            c0 = (unsigned)__popcll(mask0);
            n  = c0 + (unsigned)__popcll(mask1);
            sortable = (n >= 32u && n <= 64u);
        }

        unsigned mdup;
        if (sortable) {
            // ---- compact survivors into comp[wave][0..n) ----
            if ((mask0 >> lane) & 1ull) comp[wave][mbcnt64(mask0)] = k0r;
            if ((mask1 >> lane) & 1ull) comp[wave][c0 + mbcnt64(mask1)] = k1r;
            asm volatile("s_waitcnt lgkmcnt(0)" ::: "memory");
            unsigned k = comp[wave][lane];
            k = ((unsigned)lane < n) ? k : INFK;

            // ---- bitonic sort-64 ascending, direction-folded (21 stages) ----
            k ^= u2;
            cexd<1>(k, m1);
            k ^= s24;
            cexd<2>(k, m2); cexd<1>(k, m1);
            k ^= s48;
            cexs<4>(k, m4); cexd<2>(k, m2); cexd<1>(k, m1);
            k ^= s816;
            cexs<8>(k, m8); cexs<4>(k, m4); cexd<2>(k, m2); cexd<1>(k, m1);
            k ^= s1632;
            cexs<16>(k, m16); cexs<8>(k, m8); cexs<4>(k, m4);
            cexd<2>(k, m2); cexd<1>(k, m1);
            k ^= u32;
            cex32f(k, m32); cexs<16>(k, m16); cexs<8>(k, m8); cexs<4>(k, m4);
            cexd<2>(k, m2); cexd<1>(k, m1);

            mdup = duphalf(k, m32);
        } else {
            mdup = slow_sort(k0r, k1r);
        }

        // ---- epilogue: rank = lane&31 in both halves; 3 stores/lane ----
        const bool taken = mdup < TH;
        const int j = (int)(mdup & 127u);
        const int sel = taken ? j : i;

        float dxv = __fsub_rn(px[sel], xi);
        float dyv = __fsub_rn(py[sel], yi);
        float dzv = __fsub_rn(pz[sel], zi);
        float w = sqrtf(fmaf(dzv, dzv, fmaf(dyv, dyv, dxv * dxv)));
        const float fsrc = fbase + (float)sel;

        pA[0] = hi ? fnode : fsrc;
        pB[0] = hi ? dzv : dxv;
        pC[0] = hi ? w : dyv;
        pA += KK; pB += 3 * KK; pC += sC;
        fnode += 1.0f;
    }
}

extern "C" void kernel_launch(void* const* d_in, const int* in_sizes, int n_in,
                              void* d_out, int out_size, void* d_ws, size_t ws_size,
                              hipStream_t stream) {
    const float* pos = (const float*)d_in[0];
    float* out = (float*)d_out;
    hipLaunchKernelGGL(knn_edges_kernel, dim3(BB), dim3(256), 0, stream, pos, out);
}

// Round 16
// 39.297 us; speedup vs baseline: 1.1870x; 1.1870x over previous
//
#include <hip/hip_runtime.h>
#include <stdint.h>

// Problem constants
#define BB 1024
#define MM 128
#define KK 32
#define NEDGE (BB * MM * KK)   // 4194304
#define BPB 4                  // blocks per batch (4096 blocks: scheduler slack)
#define ROWS_PER_WAVE (MM / (4 * BPB))  // 8

#define TH  0x41C80000u        // f32 bits of 25.0  (low 7 bits zero)
#define T2  0x41480000u        // f32 bits of 12.5  (low 7 bits zero)
#define INFK 0x7F800000u

typedef unsigned int uint2v __attribute__((ext_vector_type(2)));

#define DPP1 "quad_perm:[1,0,3,2] row_mask:0xf bank_mask:0xf"   // xor 1
#define DPP2 "quad_perm:[2,3,0,1] row_mask:0xf bank_mask:0xf"   // xor 2

// ---- single-key comparators (keep-min where mask bit set) ----
template<int ST>
static __device__ __forceinline__ void cexd(unsigned& k, unsigned long long msk) {
    unsigned t0, t1;
    if constexpr (ST == 1) {
        asm("s_nop 1\n\t"
            "v_min_u32_dpp %1, %0, %0 " DPP1 "\n\t"
            "v_max_u32_dpp %2, %0, %0 " DPP1 "\n\t"
            "v_cndmask_b32 %0, %2, %1, %3"
            : "+v"(k), "=&v"(t0), "=&v"(t1) : "s"(msk));
    } else {
        asm("s_nop 1\n\t"
            "v_min_u32_dpp %1, %0, %0 " DPP2 "\n\t"
            "v_max_u32_dpp %2, %0, %0 " DPP2 "\n\t"
            "v_cndmask_b32 %0, %2, %1, %3"
            : "+v"(k), "=&v"(t0), "=&v"(t1) : "s"(msk));
    }
}

template<int ST>
static __device__ __forceinline__ void cexs(unsigned& k, unsigned long long msk) {
    unsigned p = (unsigned)__builtin_amdgcn_ds_swizzle((int)k, (ST << 10) | 0x1F);
    unsigned mn = __builtin_elementwise_min(k, p);
    unsigned mx = __builtin_elementwise_max(k, p);
    asm("v_cndmask_b32 %0, %1, %2, %3" : "=v"(k) : "v"(mx), "v"(mn), "s"(msk));
}

// stride-32 compare-exchange across the 32-lane halves
static __device__ __forceinline__ void cex32f(unsigned& k, unsigned long long msk) {
#if __has_builtin(__builtin_amdgcn_permlane32_swap)
    uint2v s = __builtin_amdgcn_permlane32_swap(k, k, false, false);
    unsigned mn = __builtin_elementwise_min(s.x, s.y);
    unsigned mx = __builtin_elementwise_max(s.x, s.y);
#else
    unsigned p = (unsigned)__shfl_xor((int)k, 32, 64);
    unsigned mn = __builtin_elementwise_min(k, p);
    unsigned mx = __builtin_elementwise_max(k, p);
#endif
    asm("v_cndmask_b32 %0, %1, %2, %3" : "=v"(k) : "v"(mx), "v"(mn), "s"(msk));
}

// min over {v[l], v[l^32]}
static __device__ __forceinline__ unsigned minxor32(unsigned k) {
#if __has_builtin(__builtin_amdgcn_permlane32_swap)
    uint2v s = __builtin_amdgcn_permlane32_swap(k, k, false, false);
    return __builtin_elementwise_min(s.x, s.y);
#else
    unsigned p = (unsigned)__shfl_xor((int)k, 32, 64);
    return __builtin_elementwise_min(k, p);
#endif
}

// duplicate lanes 0..31 into lanes 32..63
static __device__ __forceinline__ unsigned duphalf(unsigned k, unsigned long long m32) {
#if __has_builtin(__builtin_amdgcn_permlane32_swap)
    uint2v s = __builtin_amdgcn_permlane32_swap(k, k, false, false);
    unsigned partner = s.x ^ s.y ^ k;
#else
    unsigned partner = (unsigned)__shfl_xor((int)k, 32, 64);
#endif
    unsigned r;
    asm("v_cndmask_b32 %0, %1, %2, %3" : "=v"(r) : "v"(partner), "v"(k), "s"(m32));
    return r;
}

static __device__ __forceinline__ unsigned mbcnt64(unsigned long long m) {
    unsigned t = __builtin_amdgcn_mbcnt_lo((unsigned)m, 0u);
    return __builtin_amdgcn_mbcnt_hi((unsigned)(m >> 32), t);
}

// grid = BB*BPB blocks of 256 threads; each wave handles 8 rows.
// key = (f32bits(max(d2,0)) & ~0x7F) | j.
// Fast (n<=64, ~91%): compact + 21-stage sort-64.
// Refast (n>64 but 32<=n2<=64 under T2=12.5): compaction under T2 is exact
//   (>=32 survivors < T2 ==> top-32 under 25.0 all < T2) -> same sort-64.
// Slow (pathological, ~0%): round-9 two-key network.
__global__ __launch_bounds__(256, 4) void knn_edges_kernel(const float* __restrict__ pos,
                                                           float* __restrict__ out) {
    __shared__ float px[MM], py[MM], pz[MM], sqs[MM];
    __shared__ unsigned comp[4][64];
    const int blk = blockIdx.x;
    const int b = blk >> 2;            // blk / BPB
    const int sub = blk & (BPB - 1);
    const int tid = threadIdx.x;

    if (tid < MM) {
        const float* p = pos + (size_t)(b * MM + tid) * 3;
        float x = p[0], y = p[1], z = p[2];
        px[tid] = x; py[tid] = y; pz[tid] = z;
        sqs[tid] = __fadd_rn(__fadd_rn(__fmul_rn(x, x), __fmul_rn(y, y)), __fmul_rn(z, z));
    }
    __syncthreads();

    const int wave = tid >> 6;
    const int lane = tid & 63;
    const int g = lane & 31;
    const bool hi = lane >= 32;
    const unsigned upper = hi ? ~0u : 0u;

    // ---- the 6 comparator masks, anchored once into SGPR pairs ----
    unsigned long long m1  = 0x5555555555555555ull;
    unsigned long long m2  = 0x3333333333333333ull;
    unsigned long long m4  = 0x0F0F0F0F0F0F0F0Full;
    unsigned long long m8  = 0x00FF00FF00FF00FFull;
    unsigned long long m16 = 0x0000FFFF0000FFFFull;
    unsigned long long m32 = 0x00000000FFFFFFFFull;
    asm("" : "+s"(m1), "+s"(m2), "+s"(m4), "+s"(m8), "+s"(m16), "+s"(m32));

    // ---- fast-path fold constants (full-lane based) ----
    auto ff = [&](int s) -> unsigned { return (lane & s) ? ~0u : 0u; };
    const unsigned u2    = ff(2);
    const unsigned s24   = u2 ^ ff(4);
    const unsigned s48   = ff(4) ^ ff(8);
    const unsigned s816  = ff(8) ^ ff(16);
    const unsigned s1632 = ff(16) ^ ff(32);
    const unsigned u32   = ff(32);

    // ---- slow-path direction-fold constants (g-based, verified round 9) ----
    auto dmask = [&](int s) -> unsigned {
        unsigned zer = ((g & s) == 0) ? ~0u : 0u;
        return ~(zer ^ upper);   // XNOR
    };
    const unsigned f2    = dmask(2);
    const unsigned nf2   = ~f2;
    const unsigned f4c   = dmask(4);
    const unsigned f8c   = dmask(8);
    const unsigned f16c  = dmask(16);
    const unsigned f32c  = dmask(32);
    const unsigned t24   = f2 ^ f4c;
    const unsigned t48   = f4c ^ f8c;
    const unsigned t816  = f8c ^ f16c;
    const unsigned t1632 = f16c ^ f32c;
    const unsigned nf32  = ~f32c;

    // slow path (round-9 verified two-key network) — executes ~never
    auto slow_sort = [&](unsigned k0r, unsigned k1r) -> unsigned {
        unsigned K0 = k0r ^ f2;
        unsigned K1 = k1r ^ nf2;
#define SS2(ST, MSK) cexs<ST>(K0, MSK); cexs<ST>(K1, MSK);
        SS2(1, m1)
        K0 ^= t24; K1 ^= t24;
        SS2(2, m2) SS2(1, m1)
        K0 ^= t48; K1 ^= t48;
        SS2(4, m4) SS2(2, m2) SS2(1, m1)
        K0 ^= t816; K1 ^= t816;
        SS2(8, m8) SS2(4, m4) SS2(2, m2) SS2(1, m1)
        K0 ^= t1632; K1 ^= t1632;
        SS2(16, m16) SS2(8, m8) SS2(4, m4) SS2(2, m2) SS2(1, m1)
#undef SS2
        unsigned Ca = (__builtin_elementwise_min(K0 ^ f32c, K1 ^ nf32)) ^ upper;
        cexs<16>(Ca, m16); cexs<8>(Ca, m8); cexs<4>(Ca, m4);
        cexs<2>(Ca, m2);  cexs<1>(Ca, m1);
        unsigned Ma = minxor32(Ca ^ upper);
        cexs<16>(Ma, m16); cexs<8>(Ma, m8); cexs<4>(Ma, m4);
        cexs<2>(Ma, m2);  cexs<1>(Ma, m1);
        return Ma;
    };

    // per-lane candidate coordinates, hoisted across the row loop
    const int j0 = lane, j1 = lane + 64;
    const float xa = px[j0], ya = py[j0], za = pz[j0], qa = sqs[j0];
    const float xb = px[j1], yb = py[j1], zb = pz[j1], qb = sqs[j1];

    const int row0 = sub * (MM / BPB) + wave * ROWS_PER_WAVE;
    const float fbase = (float)(b * MM);   // exact in fp32

    // output streams (3 stores/lane/row):
    //  lanes <32 : pA=src (KK), pB=vec.x (3KK), pC=vec.y (3KK)
    //  lanes >=32: pA=dst (KK), pB=vec.z (3KK), pC=weight (KK)
    float* const vecbase = out + 3 * (size_t)NEDGE;
    const long e0 = (long)(b * MM + row0) * KK + g;
    float* pA = hi ? out + (size_t)NEDGE + e0 : out + e0;
    float* pB = vecbase + e0 * 3 + (hi ? 2 : 0);
    float* pC = hi ? out + 2 * (size_t)NEDGE + e0 : vecbase + e0 * 3 + 1;
    const int sC = hi ? KK : 3 * KK;

    float fnode = fbase + (float)row0;

#pragma unroll 1
    for (int ii = 0; ii < ROWS_PER_WAVE; ++ii) {
        const int i = row0 + ii;
        const float xi = px[i], yi = py[i], zi = pz[i], qi = sqs[i];

        // ---- raw candidate keys ----
        float dot0 = fmaf(xi, xa, fmaf(yi, ya, zi * za));
        unsigned k0r = (__float_as_uint(fmaxf(fmaf(-2.0f, dot0, qi + qa), 0.0f)) & 0xFFFFFF80u) | (unsigned)j0;
        float dot1 = fmaf(xi, xb, fmaf(yi, yb, zi * zb));
        unsigned k1r = (__float_as_uint(fmaxf(fmaf(-2.0f, dot1, qi + qb), 0.0f)) & 0xFFFFFF80u) | (unsigned)j1;

        // ---- census under 25.0 (wave-uniform) ----
        unsigned long long mask0 = __ballot(k0r < TH);
        unsigned long long mask1 = __ballot(k1r < TH);
        unsigned c0 = (unsigned)__popcll(mask0);
        unsigned n  = c0 + (unsigned)__popcll(mask1);

        bool sortable = (n <= 64u);
        if (!sortable) {
            // dense row: re-census under T2 = 12.5; exact when 32 <= n2 <= 64
            mask0 = __ballot(k0r < T2);
            mask1 = __ballot(k1r < T2);
            c0 = (unsigned)__popcll(mask0);
            n  = c0 + (unsigned)__popcll(mask1);
            sortable = (n >= 32u && n <= 64u);
        }

        unsigned mdup;
        if (sortable) {
            // ---- compact survivors into comp[wave][0..n) ----
            if ((mask0 >> lane) & 1ull) comp[wave][mbcnt64(mask0)] = k0r;
            if ((mask1 >> lane) & 1ull) comp[wave][c0 + mbcnt64(mask1)] = k1r;
            asm volatile("s_waitcnt lgkmcnt(0)" ::: "memory");
            unsigned k = comp[wave][lane];
            k = ((unsigned)lane < n) ? k : INFK;

            // ---- bitonic sort-64 ascending, direction-folded (21 stages) ----
            k ^= u2;
            cexd<1>(k, m1);
            k ^= s24;
            cexd<2>(k, m2); cexd<1>(k, m1);
            k ^= s48;
            cexs<4>(k, m4); cexd<2>(k, m2); cexd<1>(k, m1);
            k ^= s816;
            cexs<8>(k, m8); cexs<4>(k, m4); cexd<2>(k, m2); cexd<1>(k, m1);
            k ^= s1632;
            cexs<16>(k, m16); cexs<8>(k, m8); cexs<4>(k, m4);
            cexd<2>(k, m2); cexd<1>(k, m1);
            k ^= u32;
            cex32f(k, m32); cexs<16>(k, m16); cexs<8>(k, m8); cexs<4>(k, m4);
            cexd<2>(k, m2); cexd<1>(k, m1);

            mdup = duphalf(k, m32);
        } else {
            mdup = slow_sort(k0r, k1r);
        }

        // ---- epilogue: rank = lane&31 in both halves; 3 stores/lane ----
        const bool taken = mdup < TH;
        const int j = (int)(mdup & 127u);
        const int sel = taken ? j : i;

        float dxv = __fsub_rn(px[sel], xi);
        float dyv = __fsub_rn(py[sel], yi);
        float dzv = __fsub_rn(pz[sel], zi);
        float w = sqrtf(fmaf(dzv, dzv, fmaf(dyv, dyv, dxv * dxv)));
        const float fsrc = fbase + (float)sel;

        pA[0] = hi ? fnode : fsrc;
        pB[0] = hi ? dzv : dxv;
        pC[0] = hi ? w : dyv;
        pA += KK; pB += 3 * KK; pC += sC;
        fnode += 1.0f;
    }
}

extern "C" void kernel_launch(void* const* d_in, const int* in_sizes, int n_in,
                              void* d_out, int out_size, void* d_ws, size_t ws_size,
                              hipStream_t stream) {
    const float* pos = (const float*)d_in[0];
    float* out = (float*)d_out;
    hipLaunchKernelGGL(knn_edges_kernel, dim3(BB * BPB), dim3(256), 0, stream, pos, out);
}